// Round 2
// baseline (456.262 us; speedup 1.0000x reference)
//
#include <hip/hip_runtime.h>

// Problem constants
#define BB 32
#define CC 24
#define SSIDE 7
#define NN 49          // objects
#define DD 26          // C+2
#define QQ 2472
#define RN 256
#define NPQ 2401       // 49*49
#define TT 16          // rows per tile in g-kernel
#define NTILE 151      // ceil(2401/16)

// ws layout (float offsets)
#define QV_OFF   0                         // [32][8][256]
#define A2_OFF   65536                     // [32][49][256]
#define BJ_OFF   (A2_OFF + BB*NN*RN)       // [32][49][256]
#define PART_OFF (BJ_OFF + BB*NN*RN)       // [32][151][256]

// ---------------------------------------------------------------------------
// Kernel 1: partial sums of Qv[b,r] = sum_k qst[b,k] * W1[52+k, r]
// grid (32, 8), block 256. Each block does a 309-wide k-chunk.
// ---------------------------------------------------------------------------
__global__ void k_qv_partial(const float* __restrict__ qst,
                             const float* __restrict__ W1,
                             float* __restrict__ ws) {
    const int b = blockIdx.x, j = blockIdx.y, r = threadIdx.x;
    const int KCH = QQ / 8;                 // 309
    const int k0 = j * KCH;
    const float* q = qst + b * QQ + k0;
    const float* w = W1 + (2 * DD + k0) * RN + r;
    float acc = 0.f;
    #pragma unroll 4
    for (int k = 0; k < KCH; ++k)
        acc += q[k] * w[k * RN];
    ws[QV_OFF + (b * 8 + j) * RN + r] = acc;
}

// ---------------------------------------------------------------------------
// Kernel 2: A2[b,n,r] = x_flat[b,n] @ W1[0:26]
//           Bj[b,n,r] = x_flat[b,n] @ W1[26:52] + Qv[b,r] + b1[r]
// grid (7, 32), block 256.
// ---------------------------------------------------------------------------
__global__ void k_build_abj(const float* __restrict__ x,
                            const float* __restrict__ W1,
                            const float* __restrict__ b1,
                            float* __restrict__ ws) {
    const int ny = blockIdx.x, b = blockIdx.y, r = threadIdx.x;
    float qv = b1[r];
    #pragma unroll
    for (int j = 0; j < 8; ++j)
        qv += ws[QV_OFF + (b * 8 + j) * RN + r];

    for (int i = 0; i < 7; ++i) {
        const int n = ny * 7 + i;
        float a2 = 0.f, bj = 0.f;
        #pragma unroll
        for (int d = 0; d < DD; ++d) {
            float xv;
            if (d < CC)            xv = x[(b * CC + d) * NN + n];
            else if (d == CC)      xv = (float)(n / SSIDE) * (1.0f / 6.0f);
            else                   xv = (float)(n % SSIDE) * (1.0f / 6.0f);
            a2 += xv * W1[d * RN + r];
            bj += xv * W1[(DD + d) * RN + r];
        }
        ws[A2_OFF + (b * NN + n) * RN + r] = a2;
        ws[BJ_OFF + (b * NN + n) * RN + r] = bj + qv;
    }
}

// ---------------------------------------------------------------------------
// Kernel 3: fused g-layers. Each block = one 16-row tile of the 2401 (p,q)
// rows for one batch b. h1 = relu(A2[q] + Bj[p]); two shared layers
// h = relu(h @ Wg + bg); column-sum valid rows -> partial[b, tile, r].
// grid (151, 32), block 256. LDS 16 KB.
// ---------------------------------------------------------------------------
__global__ __launch_bounds__(256) void k_g_fused(const float* __restrict__ Wg,
                                                 const float* __restrict__ bg,
                                                 float* __restrict__ ws) {
    const int bx = blockIdx.x, b = blockIdx.y, r = threadIdx.x;
    const float* A2 = ws + A2_OFF + b * NN * RN;
    const float* Bj = ws + BJ_OFF + b * NN * RN;
    __shared__ float hs[TT * RN];           // [s=256][t=16] layout: hs[s*16+t]

    const float bgr = bg[r];
    const int pq0 = bx * TT;

    // ---- build h1 tile (rows pq0..pq0+15), pad rows -> 0 ----
    float hv[TT];
    #pragma unroll
    for (int t = 0; t < TT; ++t) {
        const int row = pq0 + t;
        float v = 0.f;
        if (row < NPQ) {
            const int p = row / NN;
            const int q = row - p * NN;
            v = fmaxf(A2[q * RN + r] + Bj[p * RN + r], 0.f);
        }
        hv[t] = v;
    }
    #pragma unroll
    for (int j4 = 0; j4 < TT / 4; ++j4) {
        float4 v4 = make_float4(hv[4*j4], hv[4*j4+1], hv[4*j4+2], hv[4*j4+3]);
        *(float4*)&hs[r * TT + 4 * j4] = v4;
    }
    __syncthreads();

    const float* wcol = Wg + r;
    float acc[TT];

    // ---- g layer 1 ----
    #pragma unroll
    for (int t = 0; t < TT; ++t) acc[t] = bgr;
    for (int s = 0; s < RN; ++s) {
        const float w = wcol[s * RN];
        const float4* hp = (const float4*)&hs[s * TT];
        float hval[TT];
        *(float4*)&hval[0]  = hp[0];
        *(float4*)&hval[4]  = hp[1];
        *(float4*)&hval[8]  = hp[2];
        *(float4*)&hval[12] = hp[3];
        #pragma unroll
        for (int t = 0; t < TT; ++t) acc[t] += hval[t] * w;
    }
    #pragma unroll
    for (int t = 0; t < TT; ++t) hv[t] = fmaxf(acc[t], 0.f);
    __syncthreads();
    #pragma unroll
    for (int j4 = 0; j4 < TT / 4; ++j4) {
        float4 v4 = make_float4(hv[4*j4], hv[4*j4+1], hv[4*j4+2], hv[4*j4+3]);
        *(float4*)&hs[r * TT + 4 * j4] = v4;
    }
    __syncthreads();

    // ---- g layer 2 + column sum ----
    #pragma unroll
    for (int t = 0; t < TT; ++t) acc[t] = bgr;
    for (int s = 0; s < RN; ++s) {
        const float w = wcol[s * RN];
        const float4* hp = (const float4*)&hs[s * TT];
        float hval[TT];
        *(float4*)&hval[0]  = hp[0];
        *(float4*)&hval[4]  = hp[1];
        *(float4*)&hval[8]  = hp[2];
        *(float4*)&hval[12] = hp[3];
        #pragma unroll
        for (int t = 0; t < TT; ++t) acc[t] += hval[t] * w;
    }
    float colsum = 0.f;
    #pragma unroll
    for (int t = 0; t < TT; ++t) {
        if (pq0 + t < NPQ) colsum += fmaxf(acc[t], 0.f);
    }
    ws[PART_OFF + (b * NTILE + bx) * RN + r] = colsum;
}

// ---------------------------------------------------------------------------
// Kernel 4: reduce partials -> x_g[b], then two f layers, write out.
// grid 32, block 256.
// ---------------------------------------------------------------------------
__global__ void k_f_reduce(const float* __restrict__ Wf,
                           const float* __restrict__ bf,
                           const float* __restrict__ ws,
                           float* __restrict__ out) {
    const int b = blockIdx.x, r = threadIdx.x;
    __shared__ float xs[RN];
    float xg = 0.f;
    for (int t = 0; t < NTILE; ++t)
        xg += ws[PART_OFF + (b * NTILE + t) * RN + r];
    xs[r] = xg;
    __syncthreads();

    float v = 0.f;
    #pragma unroll
    for (int layer = 0; layer < 2; ++layer) {
        float acc = bf[r];
        for (int s = 0; s < RN; ++s)
            acc += xs[s] * Wf[s * RN + r];
        v = fmaxf(acc, 0.f);
        __syncthreads();
        xs[r] = v;
        __syncthreads();
    }
    out[b * RN + r] = v;
}

// ---------------------------------------------------------------------------
extern "C" void kernel_launch(void* const* d_in, const int* in_sizes, int n_in,
                              void* d_out, int out_size, void* d_ws, size_t ws_size,
                              hipStream_t stream) {
    const float* x   = (const float*)d_in[0];
    const float* qst = (const float*)d_in[1];
    const float* W1  = (const float*)d_in[2];
    const float* b1  = (const float*)d_in[3];
    const float* Wg  = (const float*)d_in[4];
    const float* bg  = (const float*)d_in[5];
    const float* Wf  = (const float*)d_in[6];
    const float* bf  = (const float*)d_in[7];
    float* out = (float*)d_out;
    float* ws  = (float*)d_ws;

    k_qv_partial<<<dim3(BB, 8), RN, 0, stream>>>(qst, W1, ws);
    k_build_abj <<<dim3(7, BB), RN, 0, stream>>>(x, W1, b1, ws);
    k_g_fused   <<<dim3(NTILE, BB), RN, 0, stream>>>(Wg, bg, ws);
    k_f_reduce  <<<BB, RN, 0, stream>>>(Wf, bf, ws, out);
}

// Round 3
// 177.182 us; speedup vs baseline: 2.5751x; 2.5751x over previous
//
#include <hip/hip_runtime.h>

// Problem constants
#define BB 32
#define CC 24
#define SSIDE 7
#define NN 49          // objects
#define DD 26          // C+2
#define QQ 2472
#define RN 256
#define NPQ 2401       // 49*49
#define BM 64          // rows per block in g-kernel
#define NT2 38         // ceil(2401/64)

typedef float  f32x4  __attribute__((ext_vector_type(4)));
typedef short  short8 __attribute__((ext_vector_type(8)));
typedef __bf16 bfv8   __attribute__((ext_vector_type(8)));

// ws layout (float offsets)
#define QV_OFF   0                          // [32][8][256] f32
#define A2_OFF   65536                      // [32][49][256] f32
#define BJ_OFF   (A2_OFF + BB*NN*RN)        // [32][49][256] f32
#define WGT_OFF  (BJ_OFF + BB*NN*RN)        // WgT bf16 [256][256] = 65536 shorts = 32768 floats
#define PART_OFF (WGT_OFF + 32768)          // [32][38][256] f32

static __device__ __forceinline__ short f2bf(float f) {
    return __builtin_bit_cast(short, (__bf16)f);
}

// ---------------------------------------------------------------------------
// Kernel 1: partial sums of Qv[b,r] = sum_k qst[b,k] * W1[52+k, r]
// ---------------------------------------------------------------------------
__global__ void k_qv_partial(const float* __restrict__ qst,
                             const float* __restrict__ W1,
                             float* __restrict__ ws) {
    const int b = blockIdx.x, j = blockIdx.y, r = threadIdx.x;
    const int KCH = QQ / 8;                 // 309
    const int k0 = j * KCH;
    const float* q = qst + b * QQ + k0;
    const float* w = W1 + (2 * DD + k0) * RN + r;
    float acc = 0.f;
    #pragma unroll 4
    for (int k = 0; k < KCH; ++k)
        acc += q[k] * w[k * RN];
    ws[QV_OFF + (b * 8 + j) * RN + r] = acc;
}

// ---------------------------------------------------------------------------
// Kernel 2: A2[b,n,r] = x_flat[b,n] @ W1[0:26]
//           Bj[b,n,r] = x_flat[b,n] @ W1[26:52] + Qv[b,r] + b1[r]
// ---------------------------------------------------------------------------
__global__ void k_build_abj(const float* __restrict__ x,
                            const float* __restrict__ W1,
                            const float* __restrict__ b1,
                            float* __restrict__ ws) {
    const int ny = blockIdx.x, b = blockIdx.y, r = threadIdx.x;
    float qv = b1[r];
    #pragma unroll
    for (int j = 0; j < 8; ++j)
        qv += ws[QV_OFF + (b * 8 + j) * RN + r];

    for (int i = 0; i < 7; ++i) {
        const int n = ny * 7 + i;
        float a2 = 0.f, bj = 0.f;
        #pragma unroll
        for (int d = 0; d < DD; ++d) {
            float xv;
            if (d < CC)            xv = x[(b * CC + d) * NN + n];
            else if (d == CC)      xv = (float)(n / SSIDE) * (1.0f / 6.0f);
            else                   xv = (float)(n % SSIDE) * (1.0f / 6.0f);
            a2 += xv * W1[d * RN + r];
            bj += xv * W1[(DD + d) * RN + r];
        }
        ws[A2_OFF + (b * NN + n) * RN + r] = a2;
        ws[BJ_OFF + (b * NN + n) * RN + r] = bj + qv;
    }
}

// ---------------------------------------------------------------------------
// Kernel 2b: WgT[n][k] = bf16(Wg[k][n])   (one-time transpose+convert)
// ---------------------------------------------------------------------------
__global__ void k_wgt(const float* __restrict__ Wg, float* __restrict__ ws) {
    const int n = blockIdx.x, k = threadIdx.x;
    short* wgt = (short*)(ws + WGT_OFF);
    wgt[n * RN + k] = f2bf(Wg[k * RN + n]);
}

// ---------------------------------------------------------------------------
// Kernel 3: MFMA g-layers. Block = 64 rows of one batch; 4 waves, wave w owns
// cols [w*64, w*64+64). Swizzled bf16 h-tile in LDS; Wg^T fragments held in
// VGPRs across both layers. Pad rows masked at colsum only.
// k-convention for A/B slots: k = ks*32 + hi*8 + i (same on both operands,
// so correctness is independent of HW's internal k labeling).
// C/D layout (measured m89): col = lane&15, row = (lane>>4)*4 + reg.
// ---------------------------------------------------------------------------
__global__ __launch_bounds__(256) void k_g_mfma(const float* __restrict__ bg,
                                                float* __restrict__ ws) {
    const int bx = blockIdx.x, b = blockIdx.y;
    const int tid = threadIdx.x;
    const int lane = tid & 63, w = tid >> 6;
    const int lo = lane & 15, hi = lane >> 4;
    const int brow0 = bx * BM;
    const float* A2 = ws + A2_OFF + b * NN * RN;
    const float* Bj = ws + BJ_OFF + b * NN * RN;
    const short* wgt = (const short*)(ws + WGT_OFF);

    __shared__ short8 hbuf[BM * 32];        // [row][chunk^(row&7)], 32 KB
    short* hb = (short*)hbuf;

    // ---- build h1 tile (swizzled bf16) ----
    #pragma unroll
    for (int it = 0; it < 8; ++it) {
        const int cid = it * 256 + tid;     // 0..2047
        const int row = cid >> 5, chunk = cid & 31;
        const int grow = brow0 + row;
        short8 v8 = (short8)0;
        if (grow < NPQ) {
            const int p = grow / NN, q = grow - p * NN;
            const float4 a0 = *(const float4*)(A2 + q * RN + chunk * 8);
            const float4 a1 = *(const float4*)(A2 + q * RN + chunk * 8 + 4);
            const float4 b0 = *(const float4*)(Bj + p * RN + chunk * 8);
            const float4 b1v = *(const float4*)(Bj + p * RN + chunk * 8 + 4);
            v8[0] = f2bf(fmaxf(a0.x + b0.x, 0.f));
            v8[1] = f2bf(fmaxf(a0.y + b0.y, 0.f));
            v8[2] = f2bf(fmaxf(a0.z + b0.z, 0.f));
            v8[3] = f2bf(fmaxf(a0.w + b0.w, 0.f));
            v8[4] = f2bf(fmaxf(a1.x + b1v.x, 0.f));
            v8[5] = f2bf(fmaxf(a1.y + b1v.y, 0.f));
            v8[6] = f2bf(fmaxf(a1.z + b1v.z, 0.f));
            v8[7] = f2bf(fmaxf(a1.w + b1v.w, 0.f));
        }
        hbuf[row * 32 + (chunk ^ (row & 7))] = v8;
    }

    // ---- load Wg^T B-fragments for this wave's 64 cols, both layers ----
    const int wcol0 = w * 64;
    bfv8 bfr[4][8];
    #pragma unroll
    for (int ct = 0; ct < 4; ++ct) {
        const int n = wcol0 + ct * 16 + lo;
        #pragma unroll
        for (int ks = 0; ks < 8; ++ks)
            bfr[ct][ks] = __builtin_bit_cast(bfv8,
                *(const short8*)(wgt + n * RN + ks * 32 + hi * 8));
    }
    float bgv[4];
    #pragma unroll
    for (int ct = 0; ct < 4; ++ct)
        bgv[ct] = bg[wcol0 + ct * 16 + lo];

    __syncthreads();

    f32x4 acc[4][4];                        // [ct][rt]

    // ---- g layer 1 ----
    #pragma unroll
    for (int ct = 0; ct < 4; ++ct)
        #pragma unroll
        for (int rt = 0; rt < 4; ++rt)
            acc[ct][rt] = (f32x4){0.f, 0.f, 0.f, 0.f};
    #pragma unroll
    for (int rt = 0; rt < 4; ++rt) {
        const int row = rt * 16 + lo;
        bfv8 afr[8];
        #pragma unroll
        for (int ks = 0; ks < 8; ++ks)
            afr[ks] = __builtin_bit_cast(bfv8,
                hbuf[row * 32 + ((ks * 4 + hi) ^ (row & 7))]);
        #pragma unroll
        for (int ct = 0; ct < 4; ++ct)
            #pragma unroll
            for (int ks = 0; ks < 8; ++ks)
                acc[ct][rt] = __builtin_amdgcn_mfma_f32_16x16x32_bf16(
                    afr[ks], bfr[ct][ks], acc[ct][rt], 0, 0, 0);
    }

    // ---- bias+relu, write h2 back to swizzled LDS as bf16 ----
    __syncthreads();                        // all h1 reads done
    #pragma unroll
    for (int ct = 0; ct < 4; ++ct) {
        const int n = wcol0 + ct * 16 + lo;
        #pragma unroll
        for (int rt = 0; rt < 4; ++rt) {
            #pragma unroll
            for (int r = 0; r < 4; ++r) {
                const int row = rt * 16 + hi * 4 + r;
                const float v = fmaxf(acc[ct][rt][r] + bgv[ct], 0.f);
                hb[row * 256 + (((n >> 3) ^ (row & 7)) << 3) + (n & 7)] = f2bf(v);
            }
        }
    }
    __syncthreads();

    // ---- g layer 2 ----
    #pragma unroll
    for (int ct = 0; ct < 4; ++ct)
        #pragma unroll
        for (int rt = 0; rt < 4; ++rt)
            acc[ct][rt] = (f32x4){0.f, 0.f, 0.f, 0.f};
    #pragma unroll
    for (int rt = 0; rt < 4; ++rt) {
        const int row = rt * 16 + lo;
        bfv8 afr[8];
        #pragma unroll
        for (int ks = 0; ks < 8; ++ks)
            afr[ks] = __builtin_bit_cast(bfv8,
                hbuf[row * 32 + ((ks * 4 + hi) ^ (row & 7))]);
        #pragma unroll
        for (int ct = 0; ct < 4; ++ct)
            #pragma unroll
            for (int ks = 0; ks < 8; ++ks)
                acc[ct][rt] = __builtin_amdgcn_mfma_f32_16x16x32_bf16(
                    afr[ks], bfr[ct][ks], acc[ct][rt], 0, 0, 0);
    }

    // ---- bias+relu+mask, column-sum, cross-lane reduce, store partial ----
    float cs[4] = {0.f, 0.f, 0.f, 0.f};
    #pragma unroll
    for (int ct = 0; ct < 4; ++ct) {
        #pragma unroll
        for (int rt = 0; rt < 4; ++rt) {
            #pragma unroll
            for (int r = 0; r < 4; ++r) {
                const int grow = brow0 + rt * 16 + hi * 4 + r;
                const float v = fmaxf(acc[ct][rt][r] + bgv[ct], 0.f);
                cs[ct] += (grow < NPQ) ? v : 0.f;
            }
        }
    }
    #pragma unroll
    for (int ct = 0; ct < 4; ++ct) {
        float v = cs[ct];
        v += __shfl_xor(v, 16);
        v += __shfl_xor(v, 32);
        if (hi == 0)
            ws[PART_OFF + (b * NT2 + bx) * RN + wcol0 + ct * 16 + lo] = v;
    }
}

// ---------------------------------------------------------------------------
// Kernel 4: reduce partials -> x_g[b], then two f layers, write out.
// ---------------------------------------------------------------------------
__global__ void k_f_reduce(const float* __restrict__ Wf,
                           const float* __restrict__ bf,
                           const float* __restrict__ ws,
                           float* __restrict__ out) {
    const int b = blockIdx.x, r = threadIdx.x;
    __shared__ float xs[RN];
    float xg = 0.f;
    for (int t = 0; t < NT2; ++t)
        xg += ws[PART_OFF + (b * NT2 + t) * RN + r];
    xs[r] = xg;
    __syncthreads();

    float v = 0.f;
    #pragma unroll
    for (int layer = 0; layer < 2; ++layer) {
        float acc = bf[r];
        for (int s = 0; s < RN; ++s)
            acc += xs[s] * Wf[s * RN + r];
        v = fmaxf(acc, 0.f);
        __syncthreads();
        xs[r] = v;
        __syncthreads();
    }
    out[b * RN + r] = v;
}

// ---------------------------------------------------------------------------
extern "C" void kernel_launch(void* const* d_in, const int* in_sizes, int n_in,
                              void* d_out, int out_size, void* d_ws, size_t ws_size,
                              hipStream_t stream) {
    const float* x   = (const float*)d_in[0];
    const float* qst = (const float*)d_in[1];
    const float* W1  = (const float*)d_in[2];
    const float* b1  = (const float*)d_in[3];
    const float* Wg  = (const float*)d_in[4];
    const float* bg  = (const float*)d_in[5];
    const float* Wf  = (const float*)d_in[6];
    const float* bf  = (const float*)d_in[7];
    float* out = (float*)d_out;
    float* ws  = (float*)d_ws;

    k_qv_partial<<<dim3(BB, 8), RN, 0, stream>>>(qst, W1, ws);
    k_build_abj <<<dim3(7, BB), RN, 0, stream>>>(x, W1, b1, ws);
    k_wgt       <<<RN, RN, 0, stream>>>(Wg, ws);
    k_g_mfma    <<<dim3(NT2, BB), RN, 0, stream>>>(bg, ws);
    k_f_reduce  <<<BB, RN, 0, stream>>>(Wf, bf, ws, out);
}

// Round 5
// 150.044 us; speedup vs baseline: 3.0409x; 1.1809x over previous
//
#include <hip/hip_runtime.h>

// Problem constants
#define BB 32
#define CC 24
#define SSIDE 7
#define NN 49          // objects
#define DD 26          // C+2
#define QQ 2472
#define RN 256
#define NPQ 2401       // 49*49
#define BM 64          // rows per block in g-kernel
#define NT2 38         // ceil(2401/64)
#define NJ 24          // qv k-chunks (2472 = 24*103)
#define KCH 103

typedef float  f32x4  __attribute__((ext_vector_type(4)));
typedef short  short8 __attribute__((ext_vector_type(8)));
typedef __bf16 bfv8   __attribute__((ext_vector_type(8)));

// ws layout (float offsets). QV partials alias PART (disjoint lifetimes:
// QV written by k_prep, read by k_build_abj; PART written by k_g_mfma,
// read by k_f_reduce — stream order separates them).
#define A2_OFF   0                          // [32][49][256] f32
#define BJ_OFF   (A2_OFF + BB*NN*RN)        // [32][49][256] f32
#define WGT_OFF  (BJ_OFF + BB*NN*RN)        // WgT bf16 [256][256] = 32768 f32 slots
#define PART_OFF (WGT_OFF + 32768)          // [32][38][256] f32
#define QV_OFF   PART_OFF                   // [32][24][256] f32 (alias)

static __device__ __forceinline__ short f2bf(float f) {
    return __builtin_bit_cast(short, (__bf16)f);
}

// ---------------------------------------------------------------------------
// Kernel 1 (merged): blocks 0..767  -> Qv partials, (b = blk/24, j = blk%24)
//                    blocks 768..783 -> Wg transpose+bf16 via LDS (64x64 tile)
// ---------------------------------------------------------------------------
__global__ __launch_bounds__(256) void k_prep(const float* __restrict__ qst,
                                              const float* __restrict__ W1,
                                              const float* __restrict__ Wg,
                                              float* __restrict__ ws) {
    const int bid = blockIdx.x;
    if (bid < BB * NJ) {
        const int b = bid / NJ, j = bid % NJ, r = threadIdx.x;
        const int k0 = j * KCH;
        const float* q = qst + b * QQ + k0;
        const float* w = W1 + (2 * DD + k0) * RN + r;
        float acc = 0.f;
        #pragma unroll 4
        for (int k = 0; k < KCH; ++k)
            acc += q[k] * w[k * RN];
        ws[QV_OFF + (b * NJ + j) * RN + r] = acc;
    } else {
        // Wg transpose: tile (kt, nt) of 64x64, coalesced read AND write
        const int t = bid - BB * NJ;            // 0..15
        const int kt = (t >> 2) * 64, nt = (t & 3) * 64;
        const int tx = threadIdx.x & 63, ty = threadIdx.x >> 6;
        __shared__ short lds[64 * 65];
        short* wgt = (short*)(ws + WGT_OFF);
        #pragma unroll
        for (int i = 0; i < 16; ++i) {
            const int k = ty + i * 4;
            lds[tx * 65 + k] = f2bf(Wg[(kt + k) * RN + nt + tx]);
        }
        __syncthreads();
        #pragma unroll
        for (int i = 0; i < 16; ++i) {
            const int n = ty + i * 4;
            wgt[(nt + n) * RN + kt + tx] = lds[n * 65 + tx];
        }
    }
}

// ---------------------------------------------------------------------------
// Kernel 2: A2[b,n,r] = x_flat[b,n] @ W1[0:26]
//           Bj[b,n,r] = x_flat[b,n] @ W1[26:52] + Qv[b,r] + b1[r]
// grid (49, 32), block 256 — one object per block.
// ---------------------------------------------------------------------------
__global__ __launch_bounds__(256) void k_build_abj(const float* __restrict__ x,
                                                   const float* __restrict__ W1,
                                                   const float* __restrict__ b1,
                                                   float* __restrict__ ws) {
    const int n = blockIdx.x, b = blockIdx.y, r = threadIdx.x;
    float qv = b1[r];
    #pragma unroll 4
    for (int j = 0; j < NJ; ++j)
        qv += ws[QV_OFF + (b * NJ + j) * RN + r];

    float a2 = 0.f, bj = 0.f;
    #pragma unroll
    for (int d = 0; d < DD; ++d) {
        float xv;
        if (d < CC)            xv = x[(b * CC + d) * NN + n];
        else if (d == CC)      xv = (float)(n / SSIDE) * (1.0f / 6.0f);
        else                   xv = (float)(n % SSIDE) * (1.0f / 6.0f);
        a2 += xv * W1[d * RN + r];
        bj += xv * W1[(DD + d) * RN + r];
    }
    ws[A2_OFF + (b * NN + n) * RN + r] = a2;
    ws[BJ_OFF + (b * NN + n) * RN + r] = bj + qv;
}

// ---------------------------------------------------------------------------
// Kernel 3: MFMA g-layers. Block = 64 rows of one batch; 4 waves, wave w owns
// cols [w*64, w*64+64). Swizzled bf16 h-tile in LDS; Wg^T fragments held in
// VGPRs across both layers. Pad rows masked at colsum only.
// k-convention for A/B slots: k = ks*32 + hi*8 + i (same on both operands).
// C/D layout (measured m89): col = lane&15, row = (lane>>4)*4 + reg.
// ---------------------------------------------------------------------------
__global__ __launch_bounds__(256) void k_g_mfma(const float* __restrict__ bg,
                                                float* __restrict__ ws) {
    const int bx = blockIdx.x, b = blockIdx.y;
    const int tid = threadIdx.x;
    const int lane = tid & 63, w = tid >> 6;
    const int lo = lane & 15, hi = lane >> 4;
    const int brow0 = bx * BM;
    const float* A2 = ws + A2_OFF + b * NN * RN;
    const float* Bj = ws + BJ_OFF + b * NN * RN;
    const short* wgt = (const short*)(ws + WGT_OFF);

    __shared__ short8 hbuf[BM * 32];        // [row][chunk^(row&7)], 32 KB
    short* hb = (short*)hbuf;

    // ---- build h1 tile (swizzled bf16) ----
    #pragma unroll
    for (int it = 0; it < 8; ++it) {
        const int cid = it * 256 + tid;     // 0..2047
        const int row = cid >> 5, chunk = cid & 31;
        const int grow = brow0 + row;
        short8 v8 = (short8)0;
        if (grow < NPQ) {
            const int p = grow / NN, q = grow - p * NN;
            const float4 a0 = *(const float4*)(A2 + q * RN + chunk * 8);
            const float4 a1 = *(const float4*)(A2 + q * RN + chunk * 8 + 4);
            const float4 b0 = *(const float4*)(Bj + p * RN + chunk * 8);
            const float4 b1v = *(const float4*)(Bj + p * RN + chunk * 8 + 4);
            v8[0] = f2bf(fmaxf(a0.x + b0.x, 0.f));
            v8[1] = f2bf(fmaxf(a0.y + b0.y, 0.f));
            v8[2] = f2bf(fmaxf(a0.z + b0.z, 0.f));
            v8[3] = f2bf(fmaxf(a0.w + b0.w, 0.f));
            v8[4] = f2bf(fmaxf(a1.x + b1v.x, 0.f));
            v8[5] = f2bf(fmaxf(a1.y + b1v.y, 0.f));
            v8[6] = f2bf(fmaxf(a1.z + b1v.z, 0.f));
            v8[7] = f2bf(fmaxf(a1.w + b1v.w, 0.f));
        }
        hbuf[row * 32 + (chunk ^ (row & 7))] = v8;
    }

    // ---- load Wg^T B-fragments for this wave's 64 cols, both layers ----
    const int wcol0 = w * 64;
    bfv8 bfr[4][8];
    #pragma unroll
    for (int ct = 0; ct < 4; ++ct) {
        const int n = wcol0 + ct * 16 + lo;
        #pragma unroll
        for (int ks = 0; ks < 8; ++ks)
            bfr[ct][ks] = __builtin_bit_cast(bfv8,
                *(const short8*)(wgt + n * RN + ks * 32 + hi * 8));
    }
    float bgv[4];
    #pragma unroll
    for (int ct = 0; ct < 4; ++ct)
        bgv[ct] = bg[wcol0 + ct * 16 + lo];

    __syncthreads();

    f32x4 acc[4][4];                        // [ct][rt]

    // ---- g layer 1 ----
    #pragma unroll
    for (int ct = 0; ct < 4; ++ct)
        #pragma unroll
        for (int rt = 0; rt < 4; ++rt)
            acc[ct][rt] = (f32x4){0.f, 0.f, 0.f, 0.f};
    #pragma unroll
    for (int rt = 0; rt < 4; ++rt) {
        const int row = rt * 16 + lo;
        bfv8 afr[8];
        #pragma unroll
        for (int ks = 0; ks < 8; ++ks)
            afr[ks] = __builtin_bit_cast(bfv8,
                hbuf[row * 32 + ((ks * 4 + hi) ^ (row & 7))]);
        #pragma unroll
        for (int ct = 0; ct < 4; ++ct)
            #pragma unroll
            for (int ks = 0; ks < 8; ++ks)
                acc[ct][rt] = __builtin_amdgcn_mfma_f32_16x16x32_bf16(
                    afr[ks], bfr[ct][ks], acc[ct][rt], 0, 0, 0);
    }

    // ---- bias+relu, write h2 back to swizzled LDS as bf16 ----
    __syncthreads();                        // all h1 reads done
    #pragma unroll
    for (int ct = 0; ct < 4; ++ct) {
        const int n = wcol0 + ct * 16 + lo;
        #pragma unroll
        for (int rt = 0; rt < 4; ++rt) {
            #pragma unroll
            for (int r = 0; r < 4; ++r) {
                const int row = rt * 16 + hi * 4 + r;
                const float v = fmaxf(acc[ct][rt][r] + bgv[ct], 0.f);
                hb[row * 256 + (((n >> 3) ^ (row & 7)) << 3) + (n & 7)] = f2bf(v);
            }
        }
    }
    __syncthreads();

    // ---- g layer 2 ----
    #pragma unroll
    for (int ct = 0; ct < 4; ++ct)
        #pragma unroll
        for (int rt = 0; rt < 4; ++rt)
            acc[ct][rt] = (f32x4){0.f, 0.f, 0.f, 0.f};
    #pragma unroll
    for (int rt = 0; rt < 4; ++rt) {
        const int row = rt * 16 + lo;
        bfv8 afr[8];
        #pragma unroll
        for (int ks = 0; ks < 8; ++ks)
            afr[ks] = __builtin_bit_cast(bfv8,
                hbuf[row * 32 + ((ks * 4 + hi) ^ (row & 7))]);
        #pragma unroll
        for (int ct = 0; ct < 4; ++ct)
            #pragma unroll
            for (int ks = 0; ks < 8; ++ks)
                acc[ct][rt] = __builtin_amdgcn_mfma_f32_16x16x32_bf16(
                    afr[ks], bfr[ct][ks], acc[ct][rt], 0, 0, 0);
    }

    // ---- bias+relu+mask, column-sum, cross-lane reduce, store partial ----
    float cs[4] = {0.f, 0.f, 0.f, 0.f};
    #pragma unroll
    for (int ct = 0; ct < 4; ++ct) {
        #pragma unroll
        for (int rt = 0; rt < 4; ++rt) {
            #pragma unroll
            for (int r = 0; r < 4; ++r) {
                const int grow = brow0 + rt * 16 + hi * 4 + r;
                const float v = fmaxf(acc[ct][rt][r] + bgv[ct], 0.f);
                cs[ct] += (grow < NPQ) ? v : 0.f;
            }
        }
    }
    #pragma unroll
    for (int ct = 0; ct < 4; ++ct) {
        float v = cs[ct];
        v += __shfl_xor(v, 16);
        v += __shfl_xor(v, 32);
        if (hi == 0)
            ws[PART_OFF + (b * NT2 + bx) * RN + wcol0 + ct * 16 + lo] = v;
    }
}

// ---------------------------------------------------------------------------
// Kernel 4: reduce partials -> x_g[b], then two f layers, write out.
// ---------------------------------------------------------------------------
__global__ void k_f_reduce(const float* __restrict__ Wf,
                           const float* __restrict__ bf,
                           const float* __restrict__ ws,
                           float* __restrict__ out) {
    const int b = blockIdx.x, r = threadIdx.x;
    __shared__ float xs[RN];
    float xg = 0.f;
    for (int t = 0; t < NT2; ++t)
        xg += ws[PART_OFF + (b * NT2 + t) * RN + r];
    xs[r] = xg;
    __syncthreads();

    float v = 0.f;
    #pragma unroll
    for (int layer = 0; layer < 2; ++layer) {
        float acc = bf[r];
        for (int s = 0; s < RN; ++s)
            acc += xs[s] * Wf[s * RN + r];
        v = fmaxf(acc, 0.f);
        __syncthreads();
        xs[r] = v;
        __syncthreads();
    }
    out[b * RN + r] = v;
}

// ---------------------------------------------------------------------------
extern "C" void kernel_launch(void* const* d_in, const int* in_sizes, int n_in,
                              void* d_out, int out_size, void* d_ws, size_t ws_size,
                              hipStream_t stream) {
    const float* x   = (const float*)d_in[0];
    const float* qst = (const float*)d_in[1];
    const float* W1  = (const float*)d_in[2];
    const float* b1  = (const float*)d_in[3];
    const float* Wg  = (const float*)d_in[4];
    const float* bg  = (const float*)d_in[5];
    const float* Wf  = (const float*)d_in[6];
    const float* bf  = (const float*)d_in[7];
    float* out = (float*)d_out;
    float* ws  = (float*)d_ws;

    k_prep      <<<BB * NJ + 16, RN, 0, stream>>>(qst, W1, Wg, ws);
    k_build_abj <<<dim3(NN, BB), RN, 0, stream>>>(x, W1, b1, ws);
    k_g_mfma    <<<dim3(NT2, BB), RN, 0, stream>>>(bg, ws);
    k_f_reduce  <<<BB, RN, 0, stream>>>(Wf, bf, ws, out);
}